// Round 1
// baseline (2388.551 us; speedup 1.0000x reference)
//
#include <hip/hip_runtime.h>

#define NN_NODES 100000
#define NN_EDGES 1200000
#define CH 64

__device__ __forceinline__ float nan0(float v) { return v == v ? v : 0.0f; }

// One edge per 16-lane group; each lane handles 4 contiguous channels (float4).
__global__ __launch_bounds__(256) void scatter_kernel(
    const float* __restrict__ xin,
    const int* __restrict__ src,
    const int* __restrict__ dst,
    float* __restrict__ agg,
    float* __restrict__ cnt,   // non-null only on layer 1
    int nEdges, int doNan)
{
    int t = blockIdx.x * blockDim.x + threadIdx.x;
    int e = t >> 4;
    int lane = t & 15;
    if (e >= nEdges) return;
    int s = src[e];
    int d = dst[e];
    float4 v = *(const float4*)(xin + (size_t)s * CH + lane * 4);
    if (doNan) { v.x = nan0(v.x); v.y = nan0(v.y); v.z = nan0(v.z); v.w = nan0(v.w); }
    float* out = agg + (size_t)d * CH + lane * 4;
    atomicAdd(out + 0, v.x);
    atomicAdd(out + 1, v.y);
    atomicAdd(out + 2, v.z);
    atomicAdd(out + 3, v.w);
    if (cnt != nullptr && lane == 0) atomicAdd(cnt + d, 1.0f);
}

// 4 nodes per 256-thread block; thread (nl, j) computes output channel j of node nl.
// h[n][j] = relu( sum_k mean[n][k]*Wl[k][j] + b[j] + sum_k x[n][k]*Wr[k][j] )
__global__ __launch_bounds__(256) void node_l1_kernel(
    const float* __restrict__ x,
    const float* __restrict__ agg,
    const float* __restrict__ cnt,
    const float* __restrict__ Wl,
    const float* __restrict__ b,
    const float* __restrict__ Wr,
    float* __restrict__ h,
    int nNodes)
{
    __shared__ float sWl[64 * 64];
    __shared__ float sWr[64 * 64];
    __shared__ float sm[4][64];
    __shared__ float sx[4][64];
    int tid = threadIdx.x;
    for (int i = tid; i < 64 * 64; i += 256) { sWl[i] = Wl[i]; sWr[i] = Wr[i]; }
    int nl = tid >> 6;
    int j  = tid & 63;
    int node = blockIdx.x * 4 + nl;
    float mval = 0.0f, xval = 0.0f;
    if (node < nNodes) {
        float c = cnt[node];
        if (c < 1.0f) c = 1.0f;
        mval = agg[(size_t)node * CH + j] / c;
        xval = nan0(x[(size_t)node * CH + j]);
    }
    sm[nl][j] = mval;
    sx[nl][j] = xval;
    __syncthreads();
    if (node >= nNodes) return;
    float acc = b[j];
    #pragma unroll
    for (int k = 0; k < 64; k++)
        acc += sm[nl][k] * sWl[k * 64 + j] + sx[nl][k] * sWr[k * 64 + j];
    h[(size_t)node * CH + j] = acc > 0.0f ? acc : 0.0f;
}

// Layer 2 + fused final FC: h2 = relu(mean@Wl + b + h1@Wr); out[n] = dot(h2, Wfc) + bfc.
__global__ __launch_bounds__(256) void node_l2_kernel(
    const float* __restrict__ h1,
    const float* __restrict__ agg,
    const float* __restrict__ cnt,
    const float* __restrict__ Wl,
    const float* __restrict__ b,
    const float* __restrict__ Wr,
    const float* __restrict__ Wfc,
    const float* __restrict__ bfc,
    float* __restrict__ out,
    int nNodes)
{
    __shared__ float sWl[64 * 64];
    __shared__ float sWr[64 * 64];
    __shared__ float sm[4][64];
    __shared__ float sx[4][64];
    int tid = threadIdx.x;
    for (int i = tid; i < 64 * 64; i += 256) { sWl[i] = Wl[i]; sWr[i] = Wr[i]; }
    int nl = tid >> 6;
    int j  = tid & 63;
    int node = blockIdx.x * 4 + nl;
    float mval = 0.0f, xval = 0.0f;
    if (node < nNodes) {
        float c = cnt[node];
        if (c < 1.0f) c = 1.0f;
        mval = agg[(size_t)node * CH + j] / c;
        xval = h1[(size_t)node * CH + j];
    }
    sm[nl][j] = mval;
    sx[nl][j] = xval;
    __syncthreads();
    float acc = b[j];
    #pragma unroll
    for (int k = 0; k < 64; k++)
        acc += sm[nl][k] * sWl[k * 64 + j] + sx[nl][k] * sWr[k * 64 + j];
    float h2 = acc > 0.0f ? acc : 0.0f;
    // fused FC: per-node wave reduction (64 channels == one full wave)
    float p = h2 * Wfc[j];
    #pragma unroll
    for (int off = 32; off > 0; off >>= 1)
        p += __shfl_down(p, off, 64);
    if (j == 0 && node < nNodes)
        out[node] = p + bfc[0];
}

extern "C" void kernel_launch(void* const* d_in, const int* in_sizes, int n_in,
                              void* d_out, int out_size, void* d_ws, size_t ws_size,
                              hipStream_t stream) {
    const float* x    = (const float*)d_in[0];
    const int*   ei   = (const int*)d_in[1];     // [2, E] row-major, int32
    const float* W1l  = (const float*)d_in[2];
    const float* b1   = (const float*)d_in[3];
    const float* W1r  = (const float*)d_in[4];
    const float* W2l  = (const float*)d_in[5];
    const float* b2   = (const float*)d_in[6];
    const float* W2r  = (const float*)d_in[7];
    const float* Wfc  = (const float*)d_in[8];
    const float* bfc  = (const float*)d_in[9];
    float* out = (float*)d_out;

    const int N = NN_NODES;
    const int E = NN_EDGES;
    const int* src = ei;
    const int* dst = ei + E;

    // workspace carve: agg [N*64], h1 [N*64], cnt [N]
    float* agg = (float*)d_ws;
    float* h1  = agg + (size_t)N * CH;
    float* cnt = h1 + (size_t)N * CH;

    hipMemsetAsync(agg, 0, (size_t)N * CH * sizeof(float), stream);
    hipMemsetAsync(cnt, 0, (size_t)N * sizeof(float), stream);

    // layer 1 aggregation
    {
        long long threads = (long long)E * 16;
        int blocks = (int)((threads + 255) / 256);
        scatter_kernel<<<blocks, 256, 0, stream>>>(x, src, dst, agg, cnt, E, 1);
    }
    // layer 1 node update
    {
        int blocks = (N + 3) / 4;
        node_l1_kernel<<<blocks, 256, 0, stream>>>(x, agg, cnt, W1l, b1, W1r, h1, N);
    }
    // layer 2 aggregation (cnt is identical — reuse)
    hipMemsetAsync(agg, 0, (size_t)N * CH * sizeof(float), stream);
    {
        long long threads = (long long)E * 16;
        int blocks = (int)((threads + 255) / 256);
        scatter_kernel<<<blocks, 256, 0, stream>>>(h1, src, dst, agg, nullptr, E, 0);
    }
    // layer 2 node update + fused FC
    {
        int blocks = (N + 3) / 4;
        node_l2_kernel<<<blocks, 256, 0, stream>>>(h1, agg, cnt, W2l, b2, W2r,
                                                   Wfc, bfc, out, N);
    }
}

// Round 2
// 784.382 us; speedup vs baseline: 3.0451x; 3.0451x over previous
//
#include <hip/hip_runtime.h>

#define NN_NODES 100000
#define NN_EDGES 1200000
#define CH 64
#define SCAN_BLK 256          // elements per scan block
#define NB ((NN_NODES + SCAN_BLK - 1) / SCAN_BLK)   // 391 scan blocks

__device__ __forceinline__ float nan0(float v) { return v == v ? v : 0.0f; }

// ---------- CSR build ----------
__global__ __launch_bounds__(256) void hist_kernel(
    const int* __restrict__ dst, int* __restrict__ deg, int nEdges)
{
    int e = blockIdx.x * blockDim.x + threadIdx.x;
    if (e < nEdges) atomicAdd(&deg[dst[e]], 1);
}

// inclusive scan of 256-element chunks; write chunk scan + chunk total
__global__ __launch_bounds__(SCAN_BLK) void scan_partial_kernel(
    const int* __restrict__ deg, int* __restrict__ scan1,
    int* __restrict__ bsum, int n)
{
    __shared__ int s[SCAN_BLK];
    int t = threadIdx.x;
    int i = blockIdx.x * SCAN_BLK + t;
    s[t] = (i < n) ? deg[i] : 0;
    __syncthreads();
    for (int off = 1; off < SCAN_BLK; off <<= 1) {
        int v = (t >= off) ? s[t - off] : 0;
        __syncthreads();
        s[t] += v;
        __syncthreads();
    }
    if (i < n) scan1[i] = s[t];
    if (t == SCAN_BLK - 1) bsum[blockIdx.x] = s[t];
}

// exclusive scan of block sums (nb <= 512), one block of 512 threads
__global__ __launch_bounds__(512) void scan_bsums_kernel(
    const int* __restrict__ bsum, int* __restrict__ boff, int nb)
{
    __shared__ int s[512];
    int t = threadIdx.x;
    int own = (t < nb) ? bsum[t] : 0;
    s[t] = own;
    __syncthreads();
    for (int off = 1; off < 512; off <<= 1) {
        int v = (t >= off) ? s[t - off] : 0;
        __syncthreads();
        s[t] += v;
        __syncthreads();
    }
    if (t < nb) boff[t] = s[t] - own;   // exclusive
}

__global__ __launch_bounds__(256) void finalize_rowptr_kernel(
    const int* __restrict__ scan1, const int* __restrict__ deg,
    const int* __restrict__ boff, int* __restrict__ rowptr,
    int* __restrict__ cursor, int n, int nEdges)
{
    int i = blockIdx.x * blockDim.x + threadIdx.x;
    if (i < n) {
        int r = scan1[i] - deg[i] + boff[i >> 8];   // exclusive prefix
        rowptr[i] = r;
        cursor[i] = r;
    }
    if (i == 0) rowptr[n] = nEdges;
}

__global__ __launch_bounds__(256) void place_kernel(
    const int* __restrict__ src, const int* __restrict__ dst,
    int* __restrict__ cursor, int* __restrict__ col, int nEdges)
{
    int e = blockIdx.x * blockDim.x + threadIdx.x;
    if (e >= nEdges) return;
    int d = dst[e];
    int pos = atomicAdd(&cursor[d], 1);
    col[pos] = src[e];
}

// ---------- fused layer: gather + mean + dual GEMM + ReLU ----------
// 4 nodes per 256-thread block; node is wave-uniform (64 threads per node).
__global__ __launch_bounds__(256) void layer1_kernel(
    const float* __restrict__ x,
    const int* __restrict__ rowptr, const int* __restrict__ col,
    const float* __restrict__ Wl, const float* __restrict__ b,
    const float* __restrict__ Wr,
    float* __restrict__ h, int nNodes)
{
    __shared__ float sWl[64 * 64];
    __shared__ float sWr[64 * 64];
    __shared__ float sm[4][64];
    __shared__ float sx[4][64];
    int tid = threadIdx.x;
    for (int i = tid; i < 64 * 64; i += 256) { sWl[i] = Wl[i]; sWr[i] = Wr[i]; }
    int nl = tid >> 6;
    int j  = tid & 63;
    int node = blockIdx.x * 4 + nl;
    float mval = 0.0f, xval = 0.0f;
    if (node < nNodes) {
        int r0 = rowptr[node], r1 = rowptr[node + 1];
        float acc = 0.0f;
        for (int i = r0; i < r1; i++) {
            int s = col[i];
            acc += nan0(x[(size_t)s * CH + j]);
        }
        int deg = r1 - r0;
        mval = acc / (float)(deg > 0 ? deg : 1);
        xval = nan0(x[(size_t)node * CH + j]);
    }
    sm[nl][j] = mval;
    sx[nl][j] = xval;
    __syncthreads();
    if (node >= nNodes) return;
    float acc = b[j];
    #pragma unroll
    for (int k = 0; k < 64; k++)
        acc += sm[nl][k] * sWl[k * 64 + j] + sx[nl][k] * sWr[k * 64 + j];
    h[(size_t)node * CH + j] = acc > 0.0f ? acc : 0.0f;
}

// layer 2 + fused final FC
__global__ __launch_bounds__(256) void layer2_kernel(
    const float* __restrict__ h1,
    const int* __restrict__ rowptr, const int* __restrict__ col,
    const float* __restrict__ Wl, const float* __restrict__ b,
    const float* __restrict__ Wr,
    const float* __restrict__ Wfc, const float* __restrict__ bfc,
    float* __restrict__ out, int nNodes)
{
    __shared__ float sWl[64 * 64];
    __shared__ float sWr[64 * 64];
    __shared__ float sm[4][64];
    __shared__ float sx[4][64];
    int tid = threadIdx.x;
    for (int i = tid; i < 64 * 64; i += 256) { sWl[i] = Wl[i]; sWr[i] = Wr[i]; }
    int nl = tid >> 6;
    int j  = tid & 63;
    int node = blockIdx.x * 4 + nl;
    float mval = 0.0f, xval = 0.0f;
    if (node < nNodes) {
        int r0 = rowptr[node], r1 = rowptr[node + 1];
        float acc = 0.0f;
        for (int i = r0; i < r1; i++) {
            int s = col[i];
            acc += h1[(size_t)s * CH + j];
        }
        int deg = r1 - r0;
        mval = acc / (float)(deg > 0 ? deg : 1);
        xval = h1[(size_t)node * CH + j];
    }
    sm[nl][j] = mval;
    sx[nl][j] = xval;
    __syncthreads();
    float acc = b[j];
    #pragma unroll
    for (int k = 0; k < 64; k++)
        acc += sm[nl][k] * sWl[k * 64 + j] + sx[nl][k] * sWr[k * 64 + j];
    float h2 = acc > 0.0f ? acc : 0.0f;
    float p = h2 * Wfc[j];
    #pragma unroll
    for (int off = 32; off > 0; off >>= 1)
        p += __shfl_down(p, off, 64);
    if (j == 0 && node < nNodes)
        out[node] = p + bfc[0];
}

extern "C" void kernel_launch(void* const* d_in, const int* in_sizes, int n_in,
                              void* d_out, int out_size, void* d_ws, size_t ws_size,
                              hipStream_t stream) {
    const float* x    = (const float*)d_in[0];
    const int*   ei   = (const int*)d_in[1];     // [2, E] row-major, int32
    const float* W1l  = (const float*)d_in[2];
    const float* b1   = (const float*)d_in[3];
    const float* W1r  = (const float*)d_in[4];
    const float* W2l  = (const float*)d_in[5];
    const float* b2   = (const float*)d_in[6];
    const float* W2r  = (const float*)d_in[7];
    const float* Wfc  = (const float*)d_in[8];
    const float* bfc  = (const float*)d_in[9];
    float* out = (float*)d_out;

    const int N = NN_NODES;
    const int E = NN_EDGES;
    const int* src = ei;
    const int* dst = ei + E;

    // workspace carve
    char* ws = (char*)d_ws;
    float* h1     = (float*)ws;                 ws += (size_t)N * CH * sizeof(float);
    int*   deg    = (int*)ws;                   ws += (size_t)N * sizeof(int);
    int*   rowptr = (int*)ws;                   ws += (size_t)(N + 1) * sizeof(int);
    int*   cursor = (int*)ws;                   ws += (size_t)N * sizeof(int);
    int*   scan1  = (int*)ws;                   ws += (size_t)N * sizeof(int);
    int*   bsum   = (int*)ws;                   ws += 512 * sizeof(int);
    int*   boff   = (int*)ws;                   ws += 512 * sizeof(int);
    int*   col    = (int*)ws;                   ws += (size_t)E * sizeof(int);

    hipMemsetAsync(deg, 0, (size_t)N * sizeof(int), stream);

    hist_kernel<<<(E + 255) / 256, 256, 0, stream>>>(dst, deg, E);
    scan_partial_kernel<<<NB, SCAN_BLK, 0, stream>>>(deg, scan1, bsum, N);
    scan_bsums_kernel<<<1, 512, 0, stream>>>(bsum, boff, NB);
    finalize_rowptr_kernel<<<(N + 255) / 256, 256, 0, stream>>>(
        scan1, deg, boff, rowptr, cursor, N, E);
    place_kernel<<<(E + 255) / 256, 256, 0, stream>>>(src, dst, cursor, col, E);

    int lblocks = (N + 3) / 4;
    layer1_kernel<<<lblocks, 256, 0, stream>>>(x, rowptr, col, W1l, b1, W1r, h1, N);
    layer2_kernel<<<lblocks, 256, 0, stream>>>(h1, rowptr, col, W2l, b2, W2r,
                                               Wfc, bfc, out, N);
}

// Round 3
// 665.672 us; speedup vs baseline: 3.5882x; 1.1783x over previous
//
#include <hip/hip_runtime.h>

#define NN_NODES 100000
#define NN_EDGES 1200000
#define CH 64
#define SCAN_BLK 256
#define NB ((NN_NODES + SCAN_BLK - 1) / SCAN_BLK)   // 391 scan blocks
#define NODES_PER_BLK 16

__device__ __forceinline__ float nan0(float v) { return v == v ? v : 0.0f; }

// ---------- CSR build ----------
__global__ __launch_bounds__(256) void hist_kernel(
    const int* __restrict__ dst, int* __restrict__ deg, int nEdges)
{
    int e = blockIdx.x * blockDim.x + threadIdx.x;
    if (e < nEdges) atomicAdd(&deg[dst[e]], 1);
}

__global__ __launch_bounds__(SCAN_BLK) void scan_partial_kernel(
    const int* __restrict__ deg, int* __restrict__ scan1,
    int* __restrict__ bsum, int n)
{
    __shared__ int s[SCAN_BLK];
    int t = threadIdx.x;
    int i = blockIdx.x * SCAN_BLK + t;
    s[t] = (i < n) ? deg[i] : 0;
    __syncthreads();
    for (int off = 1; off < SCAN_BLK; off <<= 1) {
        int v = (t >= off) ? s[t - off] : 0;
        __syncthreads();
        s[t] += v;
        __syncthreads();
    }
    if (i < n) scan1[i] = s[t];
    if (t == SCAN_BLK - 1) bsum[blockIdx.x] = s[t];
}

__global__ __launch_bounds__(512) void scan_bsums_kernel(
    const int* __restrict__ bsum, int* __restrict__ boff, int nb)
{
    __shared__ int s[512];
    int t = threadIdx.x;
    int own = (t < nb) ? bsum[t] : 0;
    s[t] = own;
    __syncthreads();
    for (int off = 1; off < 512; off <<= 1) {
        int v = (t >= off) ? s[t - off] : 0;
        __syncthreads();
        s[t] += v;
        __syncthreads();
    }
    if (t < nb) boff[t] = s[t] - own;   // exclusive
}

__global__ __launch_bounds__(256) void finalize_rowptr_kernel(
    const int* __restrict__ scan1, const int* __restrict__ deg,
    const int* __restrict__ boff, int* __restrict__ rowptr,
    int* __restrict__ cursor, int n, int nEdges)
{
    int i = blockIdx.x * blockDim.x + threadIdx.x;
    if (i < n) {
        int r = scan1[i] - deg[i] + boff[i >> 8];
        rowptr[i] = r;
        cursor[i] = r;
    }
    if (i == 0) rowptr[n] = nEdges;
}

__global__ __launch_bounds__(256) void place_kernel(
    const int* __restrict__ src, const int* __restrict__ dst,
    int* __restrict__ cursor, int* __restrict__ col, int nEdges)
{
    int e = blockIdx.x * blockDim.x + threadIdx.x;
    if (e >= nEdges) return;
    int d = dst[e];
    int pos = atomicAdd(&cursor[d], 1);
    col[pos] = src[e];
}

// ---------- fused layer kernels ----------
// 256 threads = 4 waves; block owns 16 nodes; wave w gathers nodes w*4+{0..3}
// with 4x16-lane sub-groups (float4/lane, 4 edges in flight, unroll 2 -> 8).
// GEMM: thread (w, j) computes channel j of nodes {4q + w}, q=0..3.
template<int LAYER>
__global__ __launch_bounds__(256) void layer_kernel(
    const float* __restrict__ xin,
    const int* __restrict__ rowptr, const int* __restrict__ col,
    const float* __restrict__ Wl, const float* __restrict__ b,
    const float* __restrict__ Wr,
    const float* __restrict__ Wfc, const float* __restrict__ bfc,
    float* __restrict__ hout,      // layer1: h1 [N,64]; layer2: out [N]
    int nNodes)
{
    __shared__ float sWl[64 * 64];
    __shared__ float sWr[64 * 64];
    __shared__ float4 sm4[NODES_PER_BLK][16];
    __shared__ float4 sx4[NODES_PER_BLK][16];

    int tid  = threadIdx.x;
    int w    = tid >> 6;        // wave id 0..3
    int lane = tid & 63;
    int sub  = lane >> 4;       // 0..3
    int l16  = lane & 15;

    for (int i = tid; i < 64 * 64; i += 256) { sWl[i] = Wl[i]; sWr[i] = Wr[i]; }

    int n_base = blockIdx.x * NODES_PER_BLK;

    // ---- gather + mean for this wave's 4 nodes ----
    for (int nn = 0; nn < 4; nn++) {
        int ndl  = w * 4 + nn;
        int node = n_base + ndl;
        int r0 = rowptr[node], r1 = rowptr[node + 1];
        float4 a0 = {0, 0, 0, 0}, a1 = {0, 0, 0, 0};
        int i = r0 + sub;
        // unroll-by-2: up to 8 edges in flight per wave
        for (; i + 4 < r1; i += 8) {
            int s0 = col[i];
            int s1 = col[i + 4];
            float4 v0 = *(const float4*)(xin + (size_t)s0 * CH + l16 * 4);
            float4 v1 = *(const float4*)(xin + (size_t)s1 * CH + l16 * 4);
            if (LAYER == 1) {
                v0.x = nan0(v0.x); v0.y = nan0(v0.y); v0.z = nan0(v0.z); v0.w = nan0(v0.w);
                v1.x = nan0(v1.x); v1.y = nan0(v1.y); v1.z = nan0(v1.z); v1.w = nan0(v1.w);
            }
            a0.x += v0.x; a0.y += v0.y; a0.z += v0.z; a0.w += v0.w;
            a1.x += v1.x; a1.y += v1.y; a1.z += v1.z; a1.w += v1.w;
        }
        if (i < r1) {
            int s0 = col[i];
            float4 v0 = *(const float4*)(xin + (size_t)s0 * CH + l16 * 4);
            if (LAYER == 1) {
                v0.x = nan0(v0.x); v0.y = nan0(v0.y); v0.z = nan0(v0.z); v0.w = nan0(v0.w);
            }
            a0.x += v0.x; a0.y += v0.y; a0.z += v0.z; a0.w += v0.w;
        }
        a0.x += a1.x; a0.y += a1.y; a0.z += a1.z; a0.w += a1.w;
        // reduce across the 4 sub-groups (lanes ^16, ^32)
        a0.x += __shfl_xor(a0.x, 16, 64); a0.y += __shfl_xor(a0.y, 16, 64);
        a0.z += __shfl_xor(a0.z, 16, 64); a0.w += __shfl_xor(a0.w, 16, 64);
        a0.x += __shfl_xor(a0.x, 32, 64); a0.y += __shfl_xor(a0.y, 32, 64);
        a0.z += __shfl_xor(a0.z, 32, 64); a0.w += __shfl_xor(a0.w, 32, 64);
        int deg = r1 - r0;
        float inv = 1.0f / (float)(deg > 0 ? deg : 1);
        if (lane < 16) {
            float4 m; m.x = a0.x * inv; m.y = a0.y * inv; m.z = a0.z * inv; m.w = a0.w * inv;
            sm4[ndl][l16] = m;
            float4 xv = *(const float4*)(xin + (size_t)node * CH + l16 * 4);
            if (LAYER == 1) {
                xv.x = nan0(xv.x); xv.y = nan0(xv.y); xv.z = nan0(xv.z); xv.w = nan0(xv.w);
            }
            sx4[ndl][l16] = xv;
        }
    }
    __syncthreads();

    // ---- dual GEMM: 4 nodes per thread ----
    const float* smf = (const float*)sm4;
    const float* sxf = (const float*)sx4;
    int j = lane;
    float bj = b[j];
    float acc[4] = {bj, bj, bj, bj};
    #pragma unroll
    for (int k = 0; k < 64; k++) {
        float wl = sWl[k * 64 + j];
        float wr = sWr[k * 64 + j];
        #pragma unroll
        for (int q = 0; q < 4; q++) {
            int nl = 4 * q + w;
            acc[q] += smf[nl * 64 + k] * wl + sxf[nl * 64 + k] * wr;
        }
    }

    if (LAYER == 1) {
        #pragma unroll
        for (int q = 0; q < 4; q++) {
            int node = n_base + 4 * q + w;
            float v = acc[q];
            hout[(size_t)node * CH + j] = v > 0.0f ? v : 0.0f;
        }
    } else {
        float wfc = Wfc[j];
        #pragma unroll
        for (int q = 0; q < 4; q++) {
            float v = acc[q];
            v = v > 0.0f ? v : 0.0f;
            float p = v * wfc;
            #pragma unroll
            for (int off = 32; off > 0; off >>= 1)
                p += __shfl_down(p, off, 64);
            if (lane == 0) {
                int node = n_base + 4 * q + w;
                hout[node] = p + bfc[0];
            }
        }
    }
}

extern "C" void kernel_launch(void* const* d_in, const int* in_sizes, int n_in,
                              void* d_out, int out_size, void* d_ws, size_t ws_size,
                              hipStream_t stream) {
    const float* x    = (const float*)d_in[0];
    const int*   ei   = (const int*)d_in[1];
    const float* W1l  = (const float*)d_in[2];
    const float* b1   = (const float*)d_in[3];
    const float* W1r  = (const float*)d_in[4];
    const float* W2l  = (const float*)d_in[5];
    const float* b2   = (const float*)d_in[6];
    const float* W2r  = (const float*)d_in[7];
    const float* Wfc  = (const float*)d_in[8];
    const float* bfc  = (const float*)d_in[9];
    float* out = (float*)d_out;

    const int N = NN_NODES;
    const int E = NN_EDGES;
    const int* src = ei;
    const int* dst = ei + E;

    char* ws = (char*)d_ws;
    float* h1     = (float*)ws;                 ws += (size_t)N * CH * sizeof(float);
    int*   deg    = (int*)ws;                   ws += (size_t)N * sizeof(int);
    int*   rowptr = (int*)ws;                   ws += (size_t)(N + 1) * sizeof(int);
    int*   cursor = (int*)ws;                   ws += (size_t)N * sizeof(int);
    int*   scan1  = (int*)ws;                   ws += (size_t)N * sizeof(int);
    int*   bsum   = (int*)ws;                   ws += 512 * sizeof(int);
    int*   boff   = (int*)ws;                   ws += 512 * sizeof(int);
    int*   col    = (int*)ws;                   ws += (size_t)E * sizeof(int);

    hipMemsetAsync(deg, 0, (size_t)N * sizeof(int), stream);

    hist_kernel<<<(E + 255) / 256, 256, 0, stream>>>(dst, deg, E);
    scan_partial_kernel<<<NB, SCAN_BLK, 0, stream>>>(deg, scan1, bsum, N);
    scan_bsums_kernel<<<1, 512, 0, stream>>>(bsum, boff, NB);
    finalize_rowptr_kernel<<<(N + 255) / 256, 256, 0, stream>>>(
        scan1, deg, boff, rowptr, cursor, N, E);
    place_kernel<<<(E + 255) / 256, 256, 0, stream>>>(src, dst, cursor, col, E);

    int lblocks = (N + NODES_PER_BLK - 1) / NODES_PER_BLK;   // 6250
    layer_kernel<1><<<lblocks, 256, 0, stream>>>(
        x, rowptr, col, W1l, b1, W1r, nullptr, nullptr, h1, N);
    layer_kernel<2><<<lblocks, 256, 0, stream>>>(
        h1, rowptr, col, W2l, b2, W2r, Wfc, bfc, out, N);
}

// Round 4
// 569.899 us; speedup vs baseline: 4.1912x; 1.1681x over previous
//
#include <hip/hip_runtime.h>

#define NN_NODES 100000
#define NN_EDGES 1200000
#define CH 64
#define SCAN_BLK 256
#define NB ((NN_NODES + SCAN_BLK - 1) / SCAN_BLK)   // 391 scan blocks

__device__ __forceinline__ float nan0(float v) { return v == v ? v : 0.0f; }

// ---------- CSR build ----------
__global__ __launch_bounds__(256) void hist_kernel(
    const int* __restrict__ dst, int* __restrict__ deg, int nEdges)
{
    int e = blockIdx.x * blockDim.x + threadIdx.x;
    if (e < nEdges) atomicAdd(&deg[dst[e]], 1);
}

__global__ __launch_bounds__(SCAN_BLK) void scan_partial_kernel(
    const int* __restrict__ deg, int* __restrict__ scan1,
    int* __restrict__ bsum, int n)
{
    __shared__ int s[SCAN_BLK];
    int t = threadIdx.x;
    int i = blockIdx.x * SCAN_BLK + t;
    s[t] = (i < n) ? deg[i] : 0;
    __syncthreads();
    for (int off = 1; off < SCAN_BLK; off <<= 1) {
        int v = (t >= off) ? s[t - off] : 0;
        __syncthreads();
        s[t] += v;
        __syncthreads();
    }
    if (i < n) scan1[i] = s[t];
    if (t == SCAN_BLK - 1) bsum[blockIdx.x] = s[t];
}

__global__ __launch_bounds__(512) void scan_bsums_kernel(
    const int* __restrict__ bsum, int* __restrict__ boff, int nb)
{
    __shared__ int s[512];
    int t = threadIdx.x;
    int own = (t < nb) ? bsum[t] : 0;
    s[t] = own;
    __syncthreads();
    for (int off = 1; off < 512; off <<= 1) {
        int v = (t >= off) ? s[t - off] : 0;
        __syncthreads();
        s[t] += v;
        __syncthreads();
    }
    if (t < nb) boff[t] = s[t] - own;   // exclusive
}

__global__ __launch_bounds__(256) void finalize_rowptr_kernel(
    const int* __restrict__ scan1, const int* __restrict__ deg,
    const int* __restrict__ boff, int* __restrict__ rowptr,
    int* __restrict__ cursor, int n, int nEdges)
{
    int i = blockIdx.x * blockDim.x + threadIdx.x;
    if (i < n) {
        int r = scan1[i] - deg[i] + boff[i >> 8];
        rowptr[i] = r;
        cursor[i] = r;
    }
    if (i == 0) rowptr[n] = nEdges;
}

__global__ __launch_bounds__(256) void place_kernel(
    const int* __restrict__ src, const int* __restrict__ dst,
    int* __restrict__ cursor, int* __restrict__ col, int nEdges)
{
    int e = blockIdx.x * blockDim.x + threadIdx.x;
    if (e >= nEdges) return;
    int d = dst[e];
    int pos = atomicAdd(&cursor[d], 1);
    col[pos] = src[e];
}

// ---------- gather: mean of x[src] over each node's in-edges ----------
// 4 waves/block, one node per wave. Wave = 4x16-lane sub-groups; sub-group g
// handles edges r0+g, r0+g+4, ... each lane loading float4 (16 lanes x 16B
// = full 64-ch row). Unroll-by-2 => 8 edges in flight per wave. No LDS,
// minimal VGPR => high occupancy hides gather latency.
template<int LAYER>
__global__ __launch_bounds__(256) void gather_kernel(
    const float* __restrict__ xin,
    const int* __restrict__ rowptr, const int* __restrict__ col,
    float* __restrict__ mg, int nNodes)
{
    int w    = threadIdx.x >> 6;
    int lane = threadIdx.x & 63;
    int sub  = lane >> 4;
    int l16  = lane & 15;
    int node = blockIdx.x * 4 + w;
    if (node >= nNodes) return;
    int r0 = rowptr[node], r1 = rowptr[node + 1];
    float4 a0 = {0, 0, 0, 0}, a1 = {0, 0, 0, 0};
    int i = r0 + sub;
    for (; i + 4 < r1; i += 8) {
        int s0 = col[i];
        int s1 = col[i + 4];
        float4 v0 = *(const float4*)(xin + (size_t)s0 * CH + l16 * 4);
        float4 v1 = *(const float4*)(xin + (size_t)s1 * CH + l16 * 4);
        if (LAYER == 1) {
            v0.x = nan0(v0.x); v0.y = nan0(v0.y); v0.z = nan0(v0.z); v0.w = nan0(v0.w);
            v1.x = nan0(v1.x); v1.y = nan0(v1.y); v1.z = nan0(v1.z); v1.w = nan0(v1.w);
        }
        a0.x += v0.x; a0.y += v0.y; a0.z += v0.z; a0.w += v0.w;
        a1.x += v1.x; a1.y += v1.y; a1.z += v1.z; a1.w += v1.w;
    }
    if (i < r1) {
        int s0 = col[i];
        float4 v0 = *(const float4*)(xin + (size_t)s0 * CH + l16 * 4);
        if (LAYER == 1) {
            v0.x = nan0(v0.x); v0.y = nan0(v0.y); v0.z = nan0(v0.z); v0.w = nan0(v0.w);
        }
        a0.x += v0.x; a0.y += v0.y; a0.z += v0.z; a0.w += v0.w;
    }
    a0.x += a1.x; a0.y += a1.y; a0.z += a1.z; a0.w += a1.w;
    a0.x += __shfl_xor(a0.x, 16, 64); a0.y += __shfl_xor(a0.y, 16, 64);
    a0.z += __shfl_xor(a0.z, 16, 64); a0.w += __shfl_xor(a0.w, 16, 64);
    a0.x += __shfl_xor(a0.x, 32, 64); a0.y += __shfl_xor(a0.y, 32, 64);
    a0.z += __shfl_xor(a0.z, 32, 64); a0.w += __shfl_xor(a0.w, 32, 64);
    if (lane < 16) {
        int deg = r1 - r0;
        float inv = 1.0f / (float)(deg > 0 ? deg : 1);
        float4 m;
        m.x = a0.x * inv; m.y = a0.y * inv; m.z = a0.z * inv; m.w = a0.w * inv;
        *(float4*)(mg + (size_t)node * CH + l16 * 4) = m;
    }
}

// ---------- dense: h = relu(mean@Wl + b + x@Wr) [+ fused FC on layer 2] ----
// 8 nodes per 256-thread block; thread (nl, j) computes channel j of nodes
// nl and nl+4 (2 accumulators reuse each LDS weight read).
template<int LAYER>
__global__ __launch_bounds__(256) void dense_kernel(
    const float* __restrict__ xin,
    const float* __restrict__ mg,
    const float* __restrict__ Wl, const float* __restrict__ b,
    const float* __restrict__ Wr,
    const float* __restrict__ Wfc, const float* __restrict__ bfc,
    float* __restrict__ hout, int nNodes)
{
    __shared__ float sWl[64 * 64];
    __shared__ float sWr[64 * 64];
    __shared__ float sm[8][64];
    __shared__ float sx[8][64];
    int tid = threadIdx.x;
    for (int i = tid; i < 64 * 64; i += 256) { sWl[i] = Wl[i]; sWr[i] = Wr[i]; }
    int nl = tid >> 6;          // 0..3
    int j  = tid & 63;
    int n_base = blockIdx.x * 8;
    #pragma unroll
    for (int q = 0; q < 2; q++) {
        int nn = nl + 4 * q;
        int node = n_base + nn;
        float mv = 0.0f, xv = 0.0f;
        if (node < nNodes) {
            mv = mg[(size_t)node * CH + j];
            xv = xin[(size_t)node * CH + j];
            if (LAYER == 1) xv = nan0(xv);
        }
        sm[nn][j] = mv;
        sx[nn][j] = xv;
    }
    __syncthreads();
    float bj = b[j];
    float acc0 = bj, acc1 = bj;
    #pragma unroll
    for (int k = 0; k < 64; k++) {
        float wl = sWl[k * 64 + j];
        float wr = sWr[k * 64 + j];
        acc0 += sm[nl][k] * wl + sx[nl][k] * wr;
        acc1 += sm[nl + 4][k] * wl + sx[nl + 4][k] * wr;
    }
    if (LAYER == 1) {
        int node0 = n_base + nl, node1 = n_base + nl + 4;
        if (node0 < nNodes)
            hout[(size_t)node0 * CH + j] = acc0 > 0.0f ? acc0 : 0.0f;
        if (node1 < nNodes)
            hout[(size_t)node1 * CH + j] = acc1 > 0.0f ? acc1 : 0.0f;
    } else {
        float wfc = Wfc[j];
        float v0 = acc0 > 0.0f ? acc0 : 0.0f;
        float v1 = acc1 > 0.0f ? acc1 : 0.0f;
        float p0 = v0 * wfc, p1 = v1 * wfc;
        #pragma unroll
        for (int off = 32; off > 0; off >>= 1) {
            p0 += __shfl_down(p0, off, 64);
            p1 += __shfl_down(p1, off, 64);
        }
        if (j == 0) {
            int node0 = n_base + nl, node1 = n_base + nl + 4;
            if (node0 < nNodes) hout[node0] = p0 + bfc[0];
            if (node1 < nNodes) hout[node1] = p1 + bfc[0];
        }
    }
}

extern "C" void kernel_launch(void* const* d_in, const int* in_sizes, int n_in,
                              void* d_out, int out_size, void* d_ws, size_t ws_size,
                              hipStream_t stream) {
    const float* x    = (const float*)d_in[0];
    const int*   ei   = (const int*)d_in[1];
    const float* W1l  = (const float*)d_in[2];
    const float* b1   = (const float*)d_in[3];
    const float* W1r  = (const float*)d_in[4];
    const float* W2l  = (const float*)d_in[5];
    const float* b2   = (const float*)d_in[6];
    const float* W2r  = (const float*)d_in[7];
    const float* Wfc  = (const float*)d_in[8];
    const float* bfc  = (const float*)d_in[9];
    float* out = (float*)d_out;

    const int N = NN_NODES;
    const int E = NN_EDGES;
    const int* src = ei;
    const int* dst = ei + E;

    char* ws = (char*)d_ws;
    float* h1     = (float*)ws;                 ws += (size_t)N * CH * sizeof(float);
    float* mg     = (float*)ws;                 ws += (size_t)N * CH * sizeof(float);
    int*   deg    = (int*)ws;                   ws += (size_t)N * sizeof(int);
    int*   rowptr = (int*)ws;                   ws += (size_t)(N + 1) * sizeof(int);
    int*   cursor = (int*)ws;                   ws += (size_t)N * sizeof(int);
    int*   scan1  = (int*)ws;                   ws += (size_t)N * sizeof(int);
    int*   bsum   = (int*)ws;                   ws += 512 * sizeof(int);
    int*   boff   = (int*)ws;                   ws += 512 * sizeof(int);
    int*   col    = (int*)ws;                   ws += (size_t)E * sizeof(int);

    hipMemsetAsync(deg, 0, (size_t)N * sizeof(int), stream);

    hist_kernel<<<(E + 255) / 256, 256, 0, stream>>>(dst, deg, E);
    scan_partial_kernel<<<NB, SCAN_BLK, 0, stream>>>(deg, scan1, bsum, N);
    scan_bsums_kernel<<<1, 512, 0, stream>>>(bsum, boff, NB);
    finalize_rowptr_kernel<<<(N + 255) / 256, 256, 0, stream>>>(
        scan1, deg, boff, rowptr, cursor, N, E);
    place_kernel<<<(E + 255) / 256, 256, 0, stream>>>(src, dst, cursor, col, E);

    int gblocks = (N + 3) / 4;       // 25000
    int dblocks = (N + 7) / 8;       // 12500

    gather_kernel<1><<<gblocks, 256, 0, stream>>>(x, rowptr, col, mg, N);
    dense_kernel<1><<<dblocks, 256, 0, stream>>>(
        x, mg, W1l, b1, W1r, nullptr, nullptr, h1, N);
    gather_kernel<2><<<gblocks, 256, 0, stream>>>(h1, rowptr, col, mg, N);
    dense_kernel<2><<<dblocks, 256, 0, stream>>>(
        h1, mg, W2l, b2, W2r, Wfc, bfc, out, N);
}

// Round 5
// 395.072 us; speedup vs baseline: 6.0459x; 1.4425x over previous
//
#include <hip/hip_runtime.h>

#define NN_NODES 100000
#define NN_EDGES 1200000
#define CH 64
#define SCAN_BLK 256
#define NB ((NN_NODES + SCAN_BLK - 1) / SCAN_BLK)   // 391 scan blocks
#define TSTRIDE 68   // transposed-tile stride: multiple of 4 (b128 align), 8-way write conflict only at staging

__device__ __forceinline__ float nan0(float v) { return v == v ? v : 0.0f; }

// ---------- CSR build ----------
__global__ __launch_bounds__(256) void hist_kernel(
    const int* __restrict__ dst, int* __restrict__ deg, int nEdges)
{
    int e = blockIdx.x * blockDim.x + threadIdx.x;
    if (e < nEdges) atomicAdd(&deg[dst[e]], 1);
}

__global__ __launch_bounds__(SCAN_BLK) void scan_partial_kernel(
    const int* __restrict__ deg, int* __restrict__ scan1,
    int* __restrict__ bsum, int n)
{
    __shared__ int s[SCAN_BLK];
    int t = threadIdx.x;
    int i = blockIdx.x * SCAN_BLK + t;
    s[t] = (i < n) ? deg[i] : 0;
    __syncthreads();
    for (int off = 1; off < SCAN_BLK; off <<= 1) {
        int v = (t >= off) ? s[t - off] : 0;
        __syncthreads();
        s[t] += v;
        __syncthreads();
    }
    if (i < n) scan1[i] = s[t];
    if (t == SCAN_BLK - 1) bsum[blockIdx.x] = s[t];
}

__global__ __launch_bounds__(512) void scan_bsums_kernel(
    const int* __restrict__ bsum, int* __restrict__ boff, int nb)
{
    __shared__ int s[512];
    int t = threadIdx.x;
    int own = (t < nb) ? bsum[t] : 0;
    s[t] = own;
    __syncthreads();
    for (int off = 1; off < 512; off <<= 1) {
        int v = (t >= off) ? s[t - off] : 0;
        __syncthreads();
        s[t] += v;
        __syncthreads();
    }
    if (t < nb) boff[t] = s[t] - own;   // exclusive
}

__global__ __launch_bounds__(256) void finalize_rowptr_kernel(
    const int* __restrict__ scan1, const int* __restrict__ deg,
    const int* __restrict__ boff, int* __restrict__ rowptr,
    int* __restrict__ cursor, int n, int nEdges)
{
    int i = blockIdx.x * blockDim.x + threadIdx.x;
    if (i < n) {
        int r = scan1[i] - deg[i] + boff[i >> 8];
        rowptr[i] = r;
        cursor[i] = r;
    }
    if (i == 0) rowptr[n] = nEdges;
}

__global__ __launch_bounds__(256) void place_kernel(
    const int* __restrict__ src, const int* __restrict__ dst,
    int* __restrict__ cursor, int* __restrict__ col, int nEdges)
{
    int e = blockIdx.x * blockDim.x + threadIdx.x;
    if (e >= nEdges) return;
    int d = dst[e];
    int pos = atomicAdd(&cursor[d], 1);
    col[pos] = src[e];
}

// ---------- gather: mean of x[src] over each node's in-edges ----------
template<int LAYER>
__global__ __launch_bounds__(256) void gather_kernel(
    const float* __restrict__ xin,
    const int* __restrict__ rowptr, const int* __restrict__ col,
    float* __restrict__ mg, int nNodes)
{
    int w    = threadIdx.x >> 6;
    int lane = threadIdx.x & 63;
    int sub  = lane >> 4;
    int l16  = lane & 15;
    int node = blockIdx.x * 4 + w;
    if (node >= nNodes) return;
    int r0 = rowptr[node], r1 = rowptr[node + 1];
    float4 a0 = {0, 0, 0, 0}, a1 = {0, 0, 0, 0};
    int i = r0 + sub;
    for (; i + 4 < r1; i += 8) {
        int s0 = col[i];
        int s1 = col[i + 4];
        float4 v0 = *(const float4*)(xin + (size_t)s0 * CH + l16 * 4);
        float4 v1 = *(const float4*)(xin + (size_t)s1 * CH + l16 * 4);
        if (LAYER == 1) {
            v0.x = nan0(v0.x); v0.y = nan0(v0.y); v0.z = nan0(v0.z); v0.w = nan0(v0.w);
            v1.x = nan0(v1.x); v1.y = nan0(v1.y); v1.z = nan0(v1.z); v1.w = nan0(v1.w);
        }
        a0.x += v0.x; a0.y += v0.y; a0.z += v0.z; a0.w += v0.w;
        a1.x += v1.x; a1.y += v1.y; a1.z += v1.z; a1.w += v1.w;
    }
    if (i < r1) {
        int s0 = col[i];
        float4 v0 = *(const float4*)(xin + (size_t)s0 * CH + l16 * 4);
        if (LAYER == 1) {
            v0.x = nan0(v0.x); v0.y = nan0(v0.y); v0.z = nan0(v0.z); v0.w = nan0(v0.w);
        }
        a0.x += v0.x; a0.y += v0.y; a0.z += v0.z; a0.w += v0.w;
    }
    a0.x += a1.x; a0.y += a1.y; a0.z += a1.z; a0.w += a1.w;
    a0.x += __shfl_xor(a0.x, 16, 64); a0.y += __shfl_xor(a0.y, 16, 64);
    a0.z += __shfl_xor(a0.z, 16, 64); a0.w += __shfl_xor(a0.w, 16, 64);
    a0.x += __shfl_xor(a0.x, 32, 64); a0.y += __shfl_xor(a0.y, 32, 64);
    a0.z += __shfl_xor(a0.z, 32, 64); a0.w += __shfl_xor(a0.w, 32, 64);
    if (lane < 16) {
        int deg = r1 - r0;
        float inv = 1.0f / (float)(deg > 0 ? deg : 1);
        float4 m;
        m.x = a0.x * inv; m.y = a0.y * inv; m.z = a0.z * inv; m.w = a0.w * inv;
        *(float4*)(mg + (size_t)node * CH + l16 * 4) = m;
    }
}

// ---------- dense: register-tiled GEMM ----------
// Block = 64-node tile. sT holds m^T / x^T ([k][node], stride 68); sW holds
// Wl/Wr ([k][j]). Thread (tn, tj) computes 4 nodes x 4 channels; all k-loop
// loads are ds_read_b128 with heavy same-address broadcast dedup.
// Per k: 4 b128 reads feed 32 FMAs (vs 6 b32 per 4 FMA in the old version).
template<int LAYER>
__global__ __launch_bounds__(256) void dense_kernel(
    const float* __restrict__ xin,
    const float* __restrict__ mg,
    const float* __restrict__ Wl, const float* __restrict__ b,
    const float* __restrict__ Wr,
    const float* __restrict__ Wfc, const float* __restrict__ bfc,
    float* __restrict__ hout, int nNodes)
{
    __shared__ float sW[2][64][64];        // 32 KB
    __shared__ float sT[2][64][TSTRIDE];   // 34 KB
    __shared__ float sP[16][64];           // 4 KB (layer-2 FC reduction)

    int tid = threadIdx.x;
    int n_base = blockIdx.x * 64;

    // stage weights
    for (int i = tid; i < 64 * 64; i += 256) {
        ((float*)sW[0])[i] = Wl[i];
        ((float*)sW[1])[i] = Wr[i];
    }
    // stage transposed input tiles (coalesced float4 read, scalar LDS scatter)
    {
        int c4  = tid & 15;     // ch group -> ch c4*4..+3
        int nn0 = tid >> 4;     // node 0..15 (+16 per rep)
        int c = c4 * 4;
        #pragma unroll
        for (int rep = 0; rep < 4; rep++) {
            int nn = nn0 + rep * 16;
            int gn = n_base + nn;
            int cn = gn < nNodes ? gn : nNodes - 1;
            float4 mv = *(const float4*)(mg + (size_t)cn * CH + c);
            float4 xv = *(const float4*)(xin + (size_t)cn * CH + c);
            if (LAYER == 1) {
                xv.x = nan0(xv.x); xv.y = nan0(xv.y);
                xv.z = nan0(xv.z); xv.w = nan0(xv.w);
            }
            sT[0][c + 0][nn] = mv.x; sT[0][c + 1][nn] = mv.y;
            sT[0][c + 2][nn] = mv.z; sT[0][c + 3][nn] = mv.w;
            sT[1][c + 0][nn] = xv.x; sT[1][c + 1][nn] = xv.y;
            sT[1][c + 2][nn] = xv.z; sT[1][c + 3][nn] = xv.w;
        }
    }
    __syncthreads();

    int tn = tid & 15;     // node group: nodes tn*4..+3
    int tj = tid >> 4;     // ch group: channels tj*4..+3
    int tn4 = tn * 4, tj4 = tj * 4;

    float4 bv = *(const float4*)(b + tj4);
    float acc[4][4];
    #pragma unroll
    for (int ni = 0; ni < 4; ni++) {
        acc[ni][0] = bv.x; acc[ni][1] = bv.y;
        acc[ni][2] = bv.z; acc[ni][3] = bv.w;
    }

    #pragma unroll 4
    for (int k = 0; k < 64; k++) {
        float4 mv = *(const float4*)&sT[0][k][tn4];
        float4 xv = *(const float4*)&sT[1][k][tn4];
        float4 wl = *(const float4*)&sW[0][k][tj4];
        float4 wr = *(const float4*)&sW[1][k][tj4];
        const float mm[4] = {mv.x, mv.y, mv.z, mv.w};
        const float xx[4] = {xv.x, xv.y, xv.z, xv.w};
        const float ll[4] = {wl.x, wl.y, wl.z, wl.w};
        const float rr[4] = {wr.x, wr.y, wr.z, wr.w};
        #pragma unroll
        for (int ni = 0; ni < 4; ni++)
            #pragma unroll
            for (int ji = 0; ji < 4; ji++)
                acc[ni][ji] += mm[ni] * ll[ji] + xx[ni] * rr[ji];
    }

    if (LAYER == 1) {
        #pragma unroll
        for (int ni = 0; ni < 4; ni++) {
            int node = n_base + tn4 + ni;
            if (node < nNodes) {
                float4 o;
                o.x = acc[ni][0] > 0.0f ? acc[ni][0] : 0.0f;
                o.y = acc[ni][1] > 0.0f ? acc[ni][1] : 0.0f;
                o.z = acc[ni][2] > 0.0f ? acc[ni][2] : 0.0f;
                o.w = acc[ni][3] > 0.0f ? acc[ni][3] : 0.0f;
                *(float4*)(hout + (size_t)node * CH + tj4) = o;
            }
        }
    } else {
        float4 wf = *(const float4*)(Wfc + tj4);
        #pragma unroll
        for (int ni = 0; ni < 4; ni++) {
            float p = 0.0f;
            p += (acc[ni][0] > 0.0f ? acc[ni][0] : 0.0f) * wf.x;
            p += (acc[ni][1] > 0.0f ? acc[ni][1] : 0.0f) * wf.y;
            p += (acc[ni][2] > 0.0f ? acc[ni][2] : 0.0f) * wf.z;
            p += (acc[ni][3] > 0.0f ? acc[ni][3] : 0.0f) * wf.w;
            sP[tj][tn4 + ni] = p;
        }
        __syncthreads();
        if (tid < 64) {
            float s = 0.0f;
            #pragma unroll
            for (int t = 0; t < 16; t++) s += sP[t][tid];
            int node = n_base + tid;
            if (node < nNodes) hout[node] = s + bfc[0];
        }
    }
}

extern "C" void kernel_launch(void* const* d_in, const int* in_sizes, int n_in,
                              void* d_out, int out_size, void* d_ws, size_t ws_size,
                              hipStream_t stream) {
    const float* x    = (const float*)d_in[0];
    const int*   ei   = (const int*)d_in[1];
    const float* W1l  = (const float*)d_in[2];
    const float* b1   = (const float*)d_in[3];
    const float* W1r  = (const float*)d_in[4];
    const float* W2l  = (const float*)d_in[5];
    const float* b2   = (const float*)d_in[6];
    const float* W2r  = (const float*)d_in[7];
    const float* Wfc  = (const float*)d_in[8];
    const float* bfc  = (const float*)d_in[9];
    float* out = (float*)d_out;

    const int N = NN_NODES;
    const int E = NN_EDGES;
    const int* src = ei;
    const int* dst = ei + E;

    char* ws = (char*)d_ws;
    float* h1     = (float*)ws;                 ws += (size_t)N * CH * sizeof(float);
    float* mg     = (float*)ws;                 ws += (size_t)N * CH * sizeof(float);
    int*   deg    = (int*)ws;                   ws += (size_t)N * sizeof(int);
    int*   rowptr = (int*)ws;                   ws += (size_t)(N + 1) * sizeof(int);
    int*   cursor = (int*)ws;                   ws += (size_t)N * sizeof(int);
    int*   scan1  = (int*)ws;                   ws += (size_t)N * sizeof(int);
    int*   bsum   = (int*)ws;                   ws += 512 * sizeof(int);
    int*   boff   = (int*)ws;                   ws += 512 * sizeof(int);
    int*   col    = (int*)ws;                   ws += (size_t)E * sizeof(int);

    hipMemsetAsync(deg, 0, (size_t)N * sizeof(int), stream);

    hist_kernel<<<(E + 255) / 256, 256, 0, stream>>>(dst, deg, E);
    scan_partial_kernel<<<NB, SCAN_BLK, 0, stream>>>(deg, scan1, bsum, N);
    scan_bsums_kernel<<<1, 512, 0, stream>>>(bsum, boff, NB);
    finalize_rowptr_kernel<<<(N + 255) / 256, 256, 0, stream>>>(
        scan1, deg, boff, rowptr, cursor, N, E);
    place_kernel<<<(E + 255) / 256, 256, 0, stream>>>(src, dst, cursor, col, E);

    int gblocks = (N + 3) / 4;       // 25000
    int dblocks = (N + 63) / 64;     // 1563

    gather_kernel<1><<<gblocks, 256, 0, stream>>>(x, rowptr, col, mg, N);
    dense_kernel<1><<<dblocks, 256, 0, stream>>>(
        x, mg, W1l, b1, W1r, nullptr, nullptr, h1, N);
    gather_kernel<2><<<gblocks, 256, 0, stream>>>(h1, rowptr, col, mg, N);
    dense_kernel<2><<<dblocks, 256, 0, stream>>>(
        h1, mg, W2l, b2, W2r, Wfc, bfc, out, N);
}